// Round 17
// baseline (114.039 us; speedup 1.0000x reference)
//
#include <hip/hip_runtime.h>

typedef unsigned short u16;
typedef __attribute__((ext_vector_type(8))) short short8;
typedef __attribute__((ext_vector_type(4))) float floatx4;

__device__ __forceinline__ u16 f2bf(float x){
  union { float f; unsigned u; } v; v.f = x;
  unsigned r = v.u + 0x7fffu + ((v.u >> 16) & 1u);
  return (u16)(r >> 16);
}

__device__ __forceinline__ unsigned cvt_pk_bf16(float lo, float hi){
  unsigned r;
  asm("v_cvt_pk_bf16_f32 %0, %1, %2" : "=v"(r) : "v"(lo), "v"(hi));
  return r;
}

// raw v_exp_f32: args bounded (defer-max THR=8); underflow->0 wanted. No OCML fixup.
__device__ __forceinline__ float exp2_raw(float x){
  float r;
  asm("v_exp_f32 %0, %1" : "=v"(r) : "v"(x));
  return r;
}

__device__ __forceinline__ void gld16(const u16* g, u16* l){
  __builtin_amdgcn_global_load_lds(
      (const __attribute__((address_space(1))) void*)g,
      (__attribute__((address_space(3))) void*)l, 16, 0, 0);
}

#define WAIT_BAR_V3() asm volatile("s_waitcnt vmcnt(3) lgkmcnt(0)\ns_barrier" ::: "memory")
#define WAIT_BAR_V0() asm volatile("s_waitcnt vmcnt(0) lgkmcnt(0)\ns_barrier" ::: "memory")

// ---------------- fused fp32 -> bf16 convert (x + 4 weights, one launch) -------
__global__ void k_cvt_all(const float* __restrict__ x,
                          const float* __restrict__ wq, const float* __restrict__ wk,
                          const float* __restrict__ wv, const float* __restrict__ wo,
                          u16* __restrict__ xb, u16* __restrict__ wqb, u16* __restrict__ wkb,
                          u16* __restrict__ wvb, u16* __restrict__ wob){
  const int i = blockIdx.x * 256 + threadIdx.x;   // float4 index, total 2097152
  const float* s; u16* d; int off;
  if (i < 1048576) { s = x; d = xb; off = i; }
  else {
    const int j = i - 1048576;
    const int wsel = j >> 18;          // 262144 f4 per weight
    off = j & 262143;
    s = (wsel==0) ? wq : (wsel==1) ? wk : (wsel==2) ? wv : wo;
    d = (wsel==0) ? wqb : (wsel==1) ? wkb : (wsel==2) ? wvb : wob;
  }
  const float4 f = ((const float4*)s)[off];
  unsigned lo = (unsigned)f2bf(f.x) | ((unsigned)f2bf(f.y) << 16);
  unsigned hi = (unsigned)f2bf(f.z) | ((unsigned)f2bf(f.w) << 16);
  ((uint2*)d)[off] = make_uint2(lo, hi);
}

// ---------------- merged QKV GEMM: one block does Q,K,V for a 128x128 tile ------
// 256 blocks (1/CU) x 256 thr. Per phase: stage A once + Wq/Wk/Wv -> 48 MFMA.
// LDS 64KB double-buffer. acc 3x(4x4) floatx4; ~250 VGPR at 1 wave/SIMD (512 avail).
__global__ __launch_bounds__(256) void k_gemm_qkv(
    const u16* __restrict__ A,
    const u16* __restrict__ Wq, const u16* __restrict__ Wk, const u16* __restrict__ Wv,
    const float* __restrict__ bq, const float* __restrict__ bk, const float* __restrict__ bv,
    u16* __restrict__ Qo, u16* __restrict__ Ko, u16* __restrict__ Vo)
{
  const int bid = (int)blockIdx.x;
  const int xcd = bid & 7;
  const int i5  = bid >> 3;                    // 0..31
  const int xb_ = ((xcd >> 2) << 2) + (i5 & 3);        // 0..7
  const int yb_ = ((xcd & 3) << 3) + (i5 >> 2);        // 0..31

  __shared__ u16 lA[2][4096];      // [128 rows][32 k]
  __shared__ u16 lW[2][3][4096];   // [buf][mode][128 cols][32 k]

  const int tid  = threadIdx.x;
  const int row0 = yb_ * 128;
  const int col0 = xb_ * 128;

  const int srow = tid >> 2;
  const int sgp  = tid & 3;
  const int sgl  = sgp ^ ((srow >> 1) & 3);
  const u16* ga0 = A  + (row0 + srow)      * 1024 + sgl * 8;
  const u16* ga1 = A  + (row0 + srow + 64) * 1024 + sgl * 8;
  const u16* gq0 = Wq + (col0 + srow)      * 1024 + sgl * 8;
  const u16* gq1 = Wq + (col0 + srow + 64) * 1024 + sgl * 8;
  const u16* gk0 = Wk + (col0 + srow)      * 1024 + sgl * 8;
  const u16* gk1 = Wk + (col0 + srow + 64) * 1024 + sgl * 8;
  const u16* gv0 = Wv + (col0 + srow)      * 1024 + sgl * 8;
  const u16* gv1 = Wv + (col0 + srow + 64) * 1024 + sgl * 8;

  const int l  = tid & 63, w = tid >> 6;
  const int wr = w >> 1,  wc = w & 1;
  const int lr = l & 15,  grp = l >> 4;
  const int sw = (lr >> 1) & 3;
  int aoff[4], boff[4];
#pragma unroll
  for (int m = 0; m < 4; ++m) aoff[m] = (wr*64 + m*16 + lr)*32 + ((grp ^ sw) * 8);
#pragma unroll
  for (int n = 0; n < 4; ++n) boff[n] = (wc*64 + n*16 + lr)*32 + ((grp ^ sw) * 8);

  floatx4 accQ[4][4], accK[4][4], accV[4][4];
#pragma unroll
  for (int m = 0; m < 4; ++m)
#pragma unroll
    for (int n = 0; n < 4; ++n) {
      accQ[m][n] = (floatx4){0.f, 0.f, 0.f, 0.f};
      accK[m][n] = (floatx4){0.f, 0.f, 0.f, 0.f};
      accV[m][n] = (floatx4){0.f, 0.f, 0.f, 0.f};
    }

#define STAGE(buf, kt_) do { \
    const int k0_ = (kt_) * 32; \
    gld16(ga0 + k0_, &lA[(buf)][tid*8]); \
    gld16(ga1 + k0_, &lA[(buf)][2048 + tid*8]); \
    gld16(gq0 + k0_, &lW[(buf)][0][tid*8]); \
    gld16(gq1 + k0_, &lW[(buf)][0][2048 + tid*8]); \
    gld16(gk0 + k0_, &lW[(buf)][1][tid*8]); \
    gld16(gk1 + k0_, &lW[(buf)][1][2048 + tid*8]); \
    gld16(gv0 + k0_, &lW[(buf)][2][tid*8]); \
    gld16(gv1 + k0_, &lW[(buf)][2][2048 + tid*8]); \
  } while (0)

  STAGE(0, 0);
  asm volatile("s_waitcnt vmcnt(0)\ns_barrier" ::: "memory");

  for (int kt0 = 0; kt0 < 32; kt0 += 2) {
#pragma unroll
    for (int i = 0; i < 2; ++i) {              // i == buffer index (compile-time)
      const int kt = kt0 + i;
      if (kt + 1 < 32) STAGE(i ^ 1, kt + 1);   // issued at top; lands under MFMA

      short8 af[4];
#pragma unroll
      for (int m = 0; m < 4; ++m) af[m] = *(const short8*)&lA[i][aoff[m]];

      short8 bq_[4], bk_[4], bv_[4];
#pragma unroll
      for (int n = 0; n < 4; ++n) {
        bq_[n] = *(const short8*)&lW[i][0][boff[n]];
        bk_[n] = *(const short8*)&lW[i][1][boff[n]];
        bv_[n] = *(const short8*)&lW[i][2][boff[n]];
      }
#pragma unroll
      for (int m = 0; m < 4; ++m)
#pragma unroll
        for (int n = 0; n < 4; ++n) {
          accQ[m][n] = __builtin_amdgcn_mfma_f32_16x16x32_bf16(af[m], bq_[n], accQ[m][n], 0, 0, 0);
          accK[m][n] = __builtin_amdgcn_mfma_f32_16x16x32_bf16(af[m], bk_[n], accK[m][n], 0, 0, 0);
          accV[m][n] = __builtin_amdgcn_mfma_f32_16x16x32_bf16(af[m], bv_[n], accV[m][n], 0, 0, 0);
        }
      WAIT_BAR_V0();
    }
  }
#undef STAGE

  // epilogue: three outputs
#pragma unroll
  for (int n = 0; n < 4; ++n) {
    const int cg = col0 + wc*64 + n*16 + lr;
    const int h = cg >> 6, d = cg & 63;
    const float bbq = bq[cg], bbk = bk[cg], bbv = bv[cg];
#pragma unroll
    for (int m = 0; m < 4; ++m) {
#pragma unroll
      for (int j = 0; j < 4; ++j) {
        const int rg = row0 + wr*64 + m*16 + grp*4 + j;
        const int b = rg >> 11, s5 = rg & 2047;
        const int idxQK = ((b*16 + h)*2048 + s5)*64 + d;
        const int idxV  = ((b*16 + h)*64 + d)*2048 + s5;
        Qo[idxQK] = f2bf((accQ[m][n][j] + bbq) * 0.18033688011112042f); // 0.125*log2e
        Ko[idxQK] = f2bf(accK[m][n][j] + bbk);
        Vo[idxV]  = f2bf(accV[m][n][j] + bbv);
      }
    }
  }
}

// ---------------- O-proj GEMM: 64x128 tile, XCD-chunked, triple-buffered --------
__global__ __launch_bounds__(256) void k_gemm_o(
    const u16* __restrict__ A, const u16* __restrict__ W,
    const float* __restrict__ bias, float* __restrict__ Fo)
{
  const int bid = (int)blockIdx.x;
  const int xcd = bid & 7;
  const int i5  = bid >> 3;                    // 0..63
  const int xb_ = ((xcd >> 2) << 2) + (i5 & 3);        // 0..7
  const int yb_ = ((xcd & 3) << 4) + (i5 >> 2);        // 0..63

  __shared__ u16 lA[3][2048];
  __shared__ u16 lB[3][4096];

  const int tid  = threadIdx.x;
  const int row0 = yb_ * 64;
  const int col0 = xb_ * 128;

  const int srow = tid >> 2;
  const int sgp  = tid & 3;
  const int sgl  = sgp ^ ((srow >> 1) & 3);
  const u16* ga0 = A + (row0 + srow)      * 1024 + sgl * 8;
  const u16* gb0 = W + (col0 + srow)      * 1024 + sgl * 8;
  const u16* gb1 = W + (col0 + srow + 64) * 1024 + sgl * 8;

  const int l  = tid & 63, w = tid >> 6;
  const int wr = w >> 1,  wc = w & 1;
  const int lr = l & 15,  grp = l >> 4;
  const int sw = (lr >> 1) & 3;
  int aoff[2], boff[4];
#pragma unroll
  for (int m = 0; m < 2; ++m) aoff[m] = (wr*32 + m*16 + lr)*32 + ((grp ^ sw) * 8);
#pragma unroll
  for (int n = 0; n < 4; ++n) boff[n] = (wc*64 + n*16 + lr)*32 + ((grp ^ sw) * 8);

  floatx4 acc[2][4];
#pragma unroll
  for (int m = 0; m < 2; ++m)
#pragma unroll
    for (int n = 0; n < 4; ++n) acc[m][n] = (floatx4){0.f, 0.f, 0.f, 0.f};

#define STAGE(buf, kt_) do { \
    const int k0_ = (kt_) * 32; \
    gld16(ga0 + k0_, &lA[(buf)][tid*8]); \
    gld16(gb0 + k0_, &lB[(buf)][tid*8]); \
    gld16(gb1 + k0_, &lB[(buf)][2048 + tid*8]); \
  } while (0)

  STAGE(0, 0);
  STAGE(1, 1);
  asm volatile("s_waitcnt vmcnt(3)\ns_barrier" ::: "memory");

  for (int kt0 = 0; kt0 < 32; kt0 += 3) {
#pragma unroll
    for (int i = 0; i < 3; ++i) {
      const int kt = kt0 + i;
      if (kt >= 32) break;
      const bool st2 = (kt + 2 < 32);
      if (st2) STAGE((i + 2) % 3, kt + 2);
      short8 af[2], bf[4];
#pragma unroll
      for (int m = 0; m < 2; ++m) af[m] = *(const short8*)&lA[i][aoff[m]];
#pragma unroll
      for (int n = 0; n < 4; ++n) bf[n] = *(const short8*)&lB[i][boff[n]];
#pragma unroll
      for (int m = 0; m < 2; ++m)
#pragma unroll
        for (int n = 0; n < 4; ++n)
          acc[m][n] = __builtin_amdgcn_mfma_f32_16x16x32_bf16(af[m], bf[n], acc[m][n], 0, 0, 0);
      if (st2) WAIT_BAR_V3(); else WAIT_BAR_V0();
    }
  }
#undef STAGE

#pragma unroll
  for (int n = 0; n < 4; ++n) {
    const int cg = col0 + wc*64 + n*16 + lr;
    const float bb = bias[cg];
#pragma unroll
    for (int m = 0; m < 2; ++m) {
      const int rg = row0 + wr*32 + m*16 + grp*4;
#pragma unroll
      for (int j = 0; j < 4; ++j)
        Fo[(rg + j) * 1024 + cg] = acc[m][n][j] + bb;
    }
  }
}

// ---------------- flash attention (round-16: balanced blocks + THR=8) -----------
__global__ __launch_bounds__(256, 4) void k_attn(
    const u16* __restrict__ Q, const u16* __restrict__ K,
    const u16* __restrict__ V, u16* __restrict__ O)
{
  __shared__ u16 lK[2][4096];     // [64 keys][64 dk] groups-of-8 swizzled
  __shared__ u16 lV[2][4096];     // [64 dk][64 keys] (V^T) swizzled
  __shared__ u16 lP[4][1024];     // [wave][16 q][64 keys] (wave-private)

  const int tid = threadIdx.x;
  const int bid = (int)blockIdx.x;
  const int xcd = bid & 7, r = bid >> 3;       // 128 blocks per XCD
  const int k_ = r & 31, j_ = r >> 5;          // CU index within XCD, slot 0..3
  const int bh = xcd * 4 + j_;                 // 4 bh per XCD -> K/V L2-resident
  const int qt = (j_ & 1) ? k_ : (31 - k_);    // per-CU phases: 66 for all CUs

  const int l = tid & 63, w = tid >> 6;
  const int lr = l & 15, grp = l >> 4;
  const int qw0 = qt * 64 + w * 16;
  const int nkt = qt + 1;

  const u16* Qh = Q + (size_t)bh * 2048 * 64;
  const u16* Kh = K + (size_t)bh * 2048 * 64;
  const u16* Vh = V + (size_t)bh * 64 * 2048;

  const int srow = tid >> 3, sgp = tid & 7;
  const int sgl = sgp ^ (srow & 7);
  u16* lPw = &lP[w][0];
  const int swz = lr & 7;
  const int b = bh >> 4, h = bh & 15;

#define STAGEKV(buf, kt_) do { \
    gld16(Kh + ((kt_)*64 + srow     )*64 + sgl*8, &lK[(buf)][tid*8]); \
    gld16(Kh + ((kt_)*64 + srow + 32)*64 + sgl*8, &lK[(buf)][2048 + tid*8]); \
    gld16(Vh + (srow     )*2048 + (kt_)*64 + sgl*8, &lV[(buf)][tid*8]); \
    gld16(Vh + (srow + 32)*2048 + (kt_)*64 + sgl*8, &lV[(buf)][2048 + tid*8]); \
  } while (0)

  short8 qf[2];
#pragma unroll
  for (int kk = 0; kk < 2; ++kk)
    qf[kk] = *(const short8*)(Qh + (qw0 + lr)*64 + kk*32 + grp*8);

  floatx4 accO[4];                 // O^T: [d=dn*16+grp*4+j][q=lr]
  float mrow = -1e30f, lrow = 0.f; // lrow = per-lane PARTIAL (this lane's keys)
#pragma unroll
  for (int dn = 0; dn < 4; ++dn) accO[dn] = (floatx4){0.f, 0.f, 0.f, 0.f};

  STAGEKV(0, 0);
  __syncthreads();

  for (int kt0 = 0; kt0 < nkt; kt0 += 2) {
#pragma unroll
    for (int i = 0; i < 2; ++i) {              // i == buffer index (compile-time)
      const int kt = kt0 + i;
      if (kt >= nkt) break;                    // nkt block-uniform -> barrier-safe
      if (kt + 1 < nkt) STAGEKV(i ^ 1, kt + 1);
      const int kb = kt * 64;

      // S^T = K Q^T : st[n] reg j -> key = kb+n*16+grp*4+j, query = qw0+lr
      floatx4 st[4];
#pragma unroll
      for (int n = 0; n < 4; ++n) st[n] = (floatx4){0.f, 0.f, 0.f, 0.f};
#pragma unroll
      for (int n = 0; n < 4; ++n) {
        const int key = n*16 + lr;
#pragma unroll
        for (int kk = 0; kk < 2; ++kk) {
          const int gp = (kk*4 + grp) ^ (key & 7);
          short8 kf = *(const short8*)&lK[i][key*64 + gp*8];
          st[n] = __builtin_amdgcn_mfma_f32_16x16x32_bf16(kf, qf[kk], st[n], 0, 0, 0);
        }
      }

      // causal mask (only diagonal tile kt==qt is partial)
      const int lim = qw0 + lr - kb;
      if (63 > lim) {
#pragma unroll
        for (int n = 0; n < 4; ++n)
#pragma unroll
          for (int jj = 0; jj < 4; ++jj)
            if (n*16 + grp*4 + jj > lim) st[n][jj] = -1e30f;
      }

      // defer-max online softmax (T13, THR=8): allow P up to 2^8 before rescaling.
      float mt = st[0][0];
#pragma unroll
      for (int n = 0; n < 4; ++n)
#pragma unroll
        for (int jj = 0; jj < 4; ++jj) mt = fmaxf(mt, st[n][jj]);
      if (!__all(mt <= mrow + 8.0f)) {
        float mg = fmaxf(mt, __shfl_xor(mt, 16));
        mg = fmaxf(mg, __shfl_xor(mg, 32));
        const float mn = fmaxf(mrow, mg);
        const float alpha = exp2_raw(mrow - mn);
        mrow = mn;
        lrow *= alpha;
#pragma unroll
        for (int dn = 0; dn < 4; ++dn) accO[dn] *= alpha;
      }
      float ps = 0.f;
#pragma unroll
      for (int n = 0; n < 4; ++n)
#pragma unroll
        for (int jj = 0; jj < 4; ++jj) {
          const float p = exp2_raw(st[n][jj] - mrow);
          st[n][jj] = p;
          ps += p;
        }
      lrow += ps;                  // per-lane partial; reduced once in epilogue

      // pack P -> wave-private LDS [q][key], swizzled groups-of-8
#pragma unroll
      for (int n = 0; n < 4; ++n)
#pragma unroll
        for (int p2 = 0; p2 < 2; ++p2) {
          const unsigned pk = cvt_pk_bf16(st[n][2*p2], st[n][2*p2+1]);
          const int pg = (2*n + (grp >> 1)) ^ swz;
          ((unsigned*)lPw)[lr*32 + pg*4 + (grp & 1)*2 + p2] = pk;
        }

      asm volatile("s_waitcnt lgkmcnt(0)" ::: "memory");

      short8 pa[2];
#pragma unroll
      for (int kk = 0; kk < 2; ++kk)
        pa[kk] = *(const short8*)&lPw[lr*64 + (((kk*4 + grp) ^ swz) * 8)];

      // O^T += V^T P
#pragma unroll
      for (int dn = 0; dn < 4; ++dn) {
        const int d = dn*16 + lr;
#pragma unroll
        for (int kk = 0; kk < 2; ++kk) {
          const int gp = (kk*4 + grp) ^ (d & 7);
          short8 vf = *(const short8*)&lV[i][d*64 + gp*8];
          accO[dn] = __builtin_amdgcn_mfma_f32_16x16x32_bf16(vf, pa[kk], accO[dn], 0, 0, 0);
        }
      }
      __syncthreads();
    }
  }

  // epilogue: reduce lrow across the q-row's 4 lanes, write O^T
  float lt = lrow + __shfl_xor(lrow, 16);
  lt += __shfl_xor(lt, 32);
  const float inv = 1.0f / lt;
  const int token = b*2048 + qw0 + lr;
#pragma unroll
  for (int dn = 0; dn < 4; ++dn)
#pragma unroll
    for (int p2 = 0; p2 < 2; ++p2) {
      const unsigned pk = cvt_pk_bf16(accO[dn][2*p2] * inv, accO[dn][2*p2+1] * inv);
      *(unsigned*)&O[token*1024 + h*64 + dn*16 + grp*4 + 2*p2] = pk;
    }
#undef STAGEKV
}

// ---------------- launcher ----------------
extern "C" void kernel_launch(void* const* d_in, const int* in_sizes, int n_in,
                              void* d_out, int out_size, void* d_ws, size_t ws_size,
                              hipStream_t stream) {
  const float* x  = (const float*)d_in[0];
  const float* Wq = (const float*)d_in[1];
  const float* bq = (const float*)d_in[2];
  const float* Wk = (const float*)d_in[3];
  const float* bk = (const float*)d_in[4];
  const float* Wv = (const float*)d_in[5];
  const float* bv = (const float*)d_in[6];
  const float* Wo = (const float*)d_in[7];
  const float* bo = (const float*)d_in[8];
  float* out = (float*)d_out;

  char* ws = (char*)d_ws;
  u16* xb  = (u16*)(ws + 0);          // [4096][1024] bf16
  u16* wqb = (u16*)(ws + 8388608);
  u16* wkb = (u16*)(ws + 10485760);
  u16* wvb = (u16*)(ws + 12582912);
  u16* wob = (u16*)(ws + 14680064);
  u16* Qb  = (u16*)(ws + 16777216);   // [32][2048][64]
  u16* Kb  = (u16*)(ws + 25165824);   // [32][2048][64]
  u16* Vb  = (u16*)(ws + 33554432);   // [32][64][2048]
  u16* Ab  = (u16*)(ws + 41943040);   // [4096][1024]

  k_cvt_all<<<dim3(8192), 256, 0, stream>>>(x, Wq, Wk, Wv, Wo, xb, wqb, wkb, wvb, wob);

  k_gemm_qkv<<<dim3(256), 256, 0, stream>>>(xb, wqb, wkb, wvb, bq, bk, bv, Qb, Kb, Vb);

  k_attn<<<dim3(1024), 256, 0, stream>>>(Qb, Kb, Vb, Ab);

  k_gemm_o<<<dim3(512), 256, 0, stream>>>(Ab, wob, bo, out);
}

// Round 18
// 106.650 us; speedup vs baseline: 1.0693x; 1.0693x over previous
//
#include <hip/hip_runtime.h>

typedef unsigned short u16;
typedef __attribute__((ext_vector_type(8))) short short8;
typedef __attribute__((ext_vector_type(4))) float floatx4;

__device__ __forceinline__ u16 f2bf(float x){
  union { float f; unsigned u; } v; v.f = x;
  unsigned r = v.u + 0x7fffu + ((v.u >> 16) & 1u);
  return (u16)(r >> 16);
}

__device__ __forceinline__ unsigned cvt_pk_bf16(float lo, float hi){
  unsigned r;
  asm("v_cvt_pk_bf16_f32 %0, %1, %2" : "=v"(r) : "v"(lo), "v"(hi));
  return r;
}

// raw v_exp_f32: args bounded (defer-max THR=8); underflow->0 wanted. No OCML fixup.
__device__ __forceinline__ float exp2_raw(float x){
  float r;
  asm("v_exp_f32 %0, %1" : "=v"(r) : "v"(x));
  return r;
}

__device__ __forceinline__ void gld16(const u16* g, u16* l){
  __builtin_amdgcn_global_load_lds(
      (const __attribute__((address_space(1))) void*)g,
      (__attribute__((address_space(3))) void*)l, 16, 0, 0);
}

#define WAIT_BAR_V4() asm volatile("s_waitcnt vmcnt(4) lgkmcnt(0)\ns_barrier" ::: "memory")
#define WAIT_BAR_V3() asm volatile("s_waitcnt vmcnt(3) lgkmcnt(0)\ns_barrier" ::: "memory")
#define WAIT_BAR_V0() asm volatile("s_waitcnt vmcnt(0) lgkmcnt(0)\ns_barrier" ::: "memory")

// ---------------- fused fp32 -> bf16 convert (x + 4 weights, one launch) -------
__global__ void k_cvt_all(const float* __restrict__ x,
                          const float* __restrict__ wq, const float* __restrict__ wk,
                          const float* __restrict__ wv, const float* __restrict__ wo,
                          u16* __restrict__ xb, u16* __restrict__ wqb, u16* __restrict__ wkb,
                          u16* __restrict__ wvb, u16* __restrict__ wob){
  const int i = blockIdx.x * 256 + threadIdx.x;   // float4 index, total 2097152
  const float* s; u16* d; int off;
  if (i < 1048576) { s = x; d = xb; off = i; }
  else {
    const int j = i - 1048576;
    const int wsel = j >> 18;          // 262144 f4 per weight
    off = j & 262143;
    s = (wsel==0) ? wq : (wsel==1) ? wk : (wsel==2) ? wv : wo;
    d = (wsel==0) ? wqb : (wsel==1) ? wkb : (wsel==2) ? wvb : wob;
  }
  const float4 f = ((const float4*)s)[off];
  unsigned lo = (unsigned)f2bf(f.x) | ((unsigned)f2bf(f.y) << 16);
  unsigned hi = (unsigned)f2bf(f.z) | ((unsigned)f2bf(f.w) << 16);
  ((uint2*)d)[off] = make_uint2(lo, hi);
}

// ---------------- QKV GEMM: 128x128 tile, XCD-chunked, triple-buffered ----------
// (round-11/16 best: 768 blocks x 256 thr, unroll-3 compile-time buffers)
__global__ __launch_bounds__(256) void k_gemm_qkv(
    const u16* __restrict__ A,
    const u16* __restrict__ Wq, const u16* __restrict__ Wk, const u16* __restrict__ Wv,
    const float* __restrict__ bq, const float* __restrict__ bk, const float* __restrict__ bv,
    u16* __restrict__ Qo, u16* __restrict__ Ko, u16* __restrict__ Vo)
{
  const int bid = (int)blockIdx.x;
  const int xcd = bid & 7;
  const int i5  = bid >> 3;                    // 0..95
  const int xb_ = ((xcd >> 2) << 2) + (i5 & 3);        // 0..7
  const int rest = i5 >> 2;                    // 0..23
  const int yb_ = ((xcd & 3) << 3) + (rest & 7);       // 0..31
  const int mode = rest >> 3;                  // 0..2

  const u16* W      = (mode==1) ? Wk : (mode==2) ? Wv : Wq;
  const float* bias = (mode==1) ? bk : (mode==2) ? bv : bq;

  __shared__ u16 lA[3][4096];
  __shared__ u16 lB[3][4096];

  const int tid  = threadIdx.x;
  const int row0 = yb_ * 128;
  const int col0 = xb_ * 128;

  const int srow = tid >> 2;
  const int sgp  = tid & 3;
  const int sgl  = sgp ^ ((srow >> 1) & 3);
  const u16* ga0 = A + (row0 + srow)      * 1024 + sgl * 8;
  const u16* ga1 = A + (row0 + srow + 64) * 1024 + sgl * 8;
  const u16* gb0 = W + (col0 + srow)      * 1024 + sgl * 8;
  const u16* gb1 = W + (col0 + srow + 64) * 1024 + sgl * 8;

  const int l  = tid & 63, w = tid >> 6;
  const int wr = w >> 1,  wc = w & 1;
  const int lr = l & 15,  grp = l >> 4;
  const int sw = (lr >> 1) & 3;
  int aoff[4], boff[4];
#pragma unroll
  for (int m = 0; m < 4; ++m) aoff[m] = (wr*64 + m*16 + lr)*32 + ((grp ^ sw) * 8);
#pragma unroll
  for (int n = 0; n < 4; ++n) boff[n] = (wc*64 + n*16 + lr)*32 + ((grp ^ sw) * 8);

  floatx4 acc[4][4];
#pragma unroll
  for (int m = 0; m < 4; ++m)
#pragma unroll
    for (int n = 0; n < 4; ++n) acc[m][n] = (floatx4){0.f, 0.f, 0.f, 0.f};

#define STAGE(buf, kt_) do { \
    const int k0_ = (kt_) * 32; \
    gld16(ga0 + k0_, &lA[(buf)][tid*8]); \
    gld16(ga1 + k0_, &lA[(buf)][2048 + tid*8]); \
    gld16(gb0 + k0_, &lB[(buf)][tid*8]); \
    gld16(gb1 + k0_, &lB[(buf)][2048 + tid*8]); \
  } while (0)

  STAGE(0, 0);
  STAGE(1, 1);
  asm volatile("s_waitcnt vmcnt(4)\ns_barrier" ::: "memory");

  for (int kt0 = 0; kt0 < 32; kt0 += 3) {
#pragma unroll
    for (int i = 0; i < 3; ++i) {              // i == buffer index (compile-time)
      const int kt = kt0 + i;
      if (kt >= 32) break;
      const bool st2 = (kt + 2 < 32);
      if (st2) STAGE((i + 2) % 3, kt + 2);
      short8 af[4], bf[4];
#pragma unroll
      for (int m = 0; m < 4; ++m) af[m] = *(const short8*)&lA[i][aoff[m]];
#pragma unroll
      for (int n = 0; n < 4; ++n) bf[n] = *(const short8*)&lB[i][boff[n]];
#pragma unroll
      for (int m = 0; m < 4; ++m)
#pragma unroll
        for (int n = 0; n < 4; ++n)
          acc[m][n] = __builtin_amdgcn_mfma_f32_16x16x32_bf16(af[m], bf[n], acc[m][n], 0, 0, 0);
      if (st2) WAIT_BAR_V4(); else WAIT_BAR_V0();
    }
  }
#undef STAGE

  const float sc = (mode == 0) ? 0.18033688011112042f : 1.0f;  // 0.125*log2(e) for Q
  u16* dst = (mode == 0) ? Qo : (mode == 1) ? Ko : Vo;
#pragma unroll
  for (int n = 0; n < 4; ++n) {
    const int cg = col0 + wc*64 + n*16 + lr;
    const float bb = bias[cg];
    const int h = cg >> 6, d = cg & 63;
#pragma unroll
    for (int m = 0; m < 4; ++m) {
#pragma unroll
      for (int j = 0; j < 4; ++j) {
        const int rg = row0 + wr*64 + m*16 + grp*4 + j;
        const int b = rg >> 11, s5 = rg & 2047;
        const float val = (acc[m][n][j] + bb) * sc;
        int idx;
        if (mode == 2) idx = ((b*16 + h)*64 + d)*2048 + s5;
        else           idx = ((b*16 + h)*2048 + s5)*64 + d;
        dst[idx] = f2bf(val);
      }
    }
  }
}

// ---------------- O-proj GEMM: 64x128 tile, XCD-chunked, triple-buffered --------
__global__ __launch_bounds__(256) void k_gemm_o(
    const u16* __restrict__ A, const u16* __restrict__ W,
    const float* __restrict__ bias, float* __restrict__ Fo)
{
  const int bid = (int)blockIdx.x;
  const int xcd = bid & 7;
  const int i5  = bid >> 3;                    // 0..63
  const int xb_ = ((xcd >> 2) << 2) + (i5 & 3);        // 0..7
  const int yb_ = ((xcd & 3) << 4) + (i5 >> 2);        // 0..63

  __shared__ u16 lA[3][2048];
  __shared__ u16 lB[3][4096];

  const int tid  = threadIdx.x;
  const int row0 = yb_ * 64;
  const int col0 = xb_ * 128;

  const int srow = tid >> 2;
  const int sgp  = tid & 3;
  const int sgl  = sgp ^ ((srow >> 1) & 3);
  const u16* ga0 = A + (row0 + srow)      * 1024 + sgl * 8;
  const u16* gb0 = W + (col0 + srow)      * 1024 + sgl * 8;
  const u16* gb1 = W + (col0 + srow + 64) * 1024 + sgl * 8;

  const int l  = tid & 63, w = tid >> 6;
  const int wr = w >> 1,  wc = w & 1;
  const int lr = l & 15,  grp = l >> 4;
  const int sw = (lr >> 1) & 3;
  int aoff[2], boff[4];
#pragma unroll
  for (int m = 0; m < 2; ++m) aoff[m] = (wr*32 + m*16 + lr)*32 + ((grp ^ sw) * 8);
#pragma unroll
  for (int n = 0; n < 4; ++n) boff[n] = (wc*64 + n*16 + lr)*32 + ((grp ^ sw) * 8);

  floatx4 acc[2][4];
#pragma unroll
  for (int m = 0; m < 2; ++m)
#pragma unroll
    for (int n = 0; n < 4; ++n) acc[m][n] = (floatx4){0.f, 0.f, 0.f, 0.f};

#define STAGE(buf, kt_) do { \
    const int k0_ = (kt_) * 32; \
    gld16(ga0 + k0_, &lA[(buf)][tid*8]); \
    gld16(gb0 + k0_, &lB[(buf)][tid*8]); \
    gld16(gb1 + k0_, &lB[(buf)][2048 + tid*8]); \
  } while (0)

  STAGE(0, 0);
  STAGE(1, 1);
  asm volatile("s_waitcnt vmcnt(3)\ns_barrier" ::: "memory");

  for (int kt0 = 0; kt0 < 32; kt0 += 3) {
#pragma unroll
    for (int i = 0; i < 3; ++i) {
      const int kt = kt0 + i;
      if (kt >= 32) break;
      const bool st2 = (kt + 2 < 32);
      if (st2) STAGE((i + 2) % 3, kt + 2);
      short8 af[2], bf[4];
#pragma unroll
      for (int m = 0; m < 2; ++m) af[m] = *(const short8*)&lA[i][aoff[m]];
#pragma unroll
      for (int n = 0; n < 4; ++n) bf[n] = *(const short8*)&lB[i][boff[n]];
#pragma unroll
      for (int m = 0; m < 2; ++m)
#pragma unroll
        for (int n = 0; n < 4; ++n)
          acc[m][n] = __builtin_amdgcn_mfma_f32_16x16x32_bf16(af[m], bf[n], acc[m][n], 0, 0, 0);
      if (st2) WAIT_BAR_V3(); else WAIT_BAR_V0();
    }
  }
#undef STAGE

#pragma unroll
  for (int n = 0; n < 4; ++n) {
    const int cg = col0 + wc*64 + n*16 + lr;
    const float bb = bias[cg];
#pragma unroll
    for (int m = 0; m < 2; ++m) {
      const int rg = row0 + wr*32 + m*16 + grp*4;
#pragma unroll
      for (int j = 0; j < 4; ++j)
        Fo[(rg + j) * 1024 + cg] = acc[m][n][j] + bb;
    }
  }
}

// ---------------- flash attention (round-16 best: balanced blocks + THR=8) ------
// 1024 blocks x 256 thr (4 waves x 16 q), one q-tile per block, 40KB LDS.
// CU k per XCD hosts r={k,k+32,k+64,k+96} -> qt={31-k,k,31-k,k}: 66 phases/CU.
__global__ __launch_bounds__(256, 4) void k_attn(
    const u16* __restrict__ Q, const u16* __restrict__ K,
    const u16* __restrict__ V, u16* __restrict__ O)
{
  __shared__ u16 lK[2][4096];     // [64 keys][64 dk] groups-of-8 swizzled
  __shared__ u16 lV[2][4096];     // [64 dk][64 keys] (V^T) swizzled
  __shared__ u16 lP[4][1024];     // [wave][16 q][64 keys] (wave-private)

  const int tid = threadIdx.x;
  const int bid = (int)blockIdx.x;
  const int xcd = bid & 7, r = bid >> 3;       // 128 blocks per XCD
  const int k_ = r & 31, j_ = r >> 5;          // CU index within XCD, slot 0..3
  const int bh = xcd * 4 + j_;                 // 4 bh per XCD -> K/V L2-resident
  const int qt = (j_ & 1) ? k_ : (31 - k_);    // per-CU phases: 66 for all CUs

  const int l = tid & 63, w = tid >> 6;
  const int lr = l & 15, grp = l >> 4;
  const int qw0 = qt * 64 + w * 16;
  const int nkt = qt + 1;

  const u16* Qh = Q + (size_t)bh * 2048 * 64;
  const u16* Kh = K + (size_t)bh * 2048 * 64;
  const u16* Vh = V + (size_t)bh * 64 * 2048;

  const int srow = tid >> 3, sgp = tid & 7;
  const int sgl = sgp ^ (srow & 7);
  u16* lPw = &lP[w][0];
  const int swz = lr & 7;
  const int b = bh >> 4, h = bh & 15;

#define STAGEKV(buf, kt_) do { \
    gld16(Kh + ((kt_)*64 + srow     )*64 + sgl*8, &lK[(buf)][tid*8]); \
    gld16(Kh + ((kt_)*64 + srow + 32)*64 + sgl*8, &lK[(buf)][2048 + tid*8]); \
    gld16(Vh + (srow     )*2048 + (kt_)*64 + sgl*8, &lV[(buf)][tid*8]); \
    gld16(Vh + (srow + 32)*2048 + (kt_)*64 + sgl*8, &lV[(buf)][2048 + tid*8]); \
  } while (0)

  short8 qf[2];
#pragma unroll
  for (int kk = 0; kk < 2; ++kk)
    qf[kk] = *(const short8*)(Qh + (qw0 + lr)*64 + kk*32 + grp*8);

  floatx4 accO[4];                 // O^T: [d=dn*16+grp*4+j][q=lr]
  float mrow = -1e30f, lrow = 0.f; // lrow = per-lane PARTIAL (this lane's keys)
#pragma unroll
  for (int dn = 0; dn < 4; ++dn) accO[dn] = (floatx4){0.f, 0.f, 0.f, 0.f};

  STAGEKV(0, 0);
  __syncthreads();

  for (int kt0 = 0; kt0 < nkt; kt0 += 2) {
#pragma unroll
    for (int i = 0; i < 2; ++i) {              // i == buffer index (compile-time)
      const int kt = kt0 + i;
      if (kt >= nkt) break;                    // nkt block-uniform -> barrier-safe
      if (kt + 1 < nkt) STAGEKV(i ^ 1, kt + 1);
      const int kb = kt * 64;

      // S^T = K Q^T : st[n] reg j -> key = kb+n*16+grp*4+j, query = qw0+lr
      floatx4 st[4];
#pragma unroll
      for (int n = 0; n < 4; ++n) st[n] = (floatx4){0.f, 0.f, 0.f, 0.f};
#pragma unroll
      for (int n = 0; n < 4; ++n) {
        const int key = n*16 + lr;
#pragma unroll
        for (int kk = 0; kk < 2; ++kk) {
          const int gp = (kk*4 + grp) ^ (key & 7);
          short8 kf = *(const short8*)&lK[i][key*64 + gp*8];
          st[n] = __builtin_amdgcn_mfma_f32_16x16x32_bf16(kf, qf[kk], st[n], 0, 0, 0);
        }
      }

      // causal mask (only diagonal tile kt==qt is partial)
      const int lim = qw0 + lr - kb;
      if (63 > lim) {
#pragma unroll
        for (int n = 0; n < 4; ++n)
#pragma unroll
          for (int jj = 0; jj < 4; ++jj)
            if (n*16 + grp*4 + jj > lim) st[n][jj] = -1e30f;
      }

      // defer-max online softmax (T13, THR=8): allow P up to 2^8 before rescaling.
      float mt = st[0][0];
#pragma unroll
      for (int n = 0; n < 4; ++n)
#pragma unroll
        for (int jj = 0; jj < 4; ++jj) mt = fmaxf(mt, st[n][jj]);
      if (!__all(mt <= mrow + 8.0f)) {
        float mg = fmaxf(mt, __shfl_xor(mt, 16));
        mg = fmaxf(mg, __shfl_xor(mg, 32));
        const float mn = fmaxf(mrow, mg);
        const float alpha = exp2_raw(mrow - mn);
        mrow = mn;
        lrow *= alpha;
#pragma unroll
        for (int dn = 0; dn < 4; ++dn) accO[dn] *= alpha;
      }
      float ps = 0.f;
#pragma unroll
      for (int n = 0; n < 4; ++n)
#pragma unroll
        for (int jj = 0; jj < 4; ++jj) {
          const float p = exp2_raw(st[n][jj] - mrow);
          st[n][jj] = p;
          ps += p;
        }
      lrow += ps;                  // per-lane partial; reduced once in epilogue

      // pack P -> wave-private LDS [q][key], swizzled groups-of-8
#pragma unroll
      for (int n = 0; n < 4; ++n)
#pragma unroll
        for (int p2 = 0; p2 < 2; ++p2) {
          const unsigned pk = cvt_pk_bf16(st[n][2*p2], st[n][2*p2+1]);
          const int pg = (2*n + (grp >> 1)) ^ swz;
          ((unsigned*)lPw)[lr*32 + pg*4 + (grp & 1)*2 + p2] = pk;
        }

      asm volatile("s_waitcnt lgkmcnt(0)" ::: "memory");

      short8 pa[2];
#pragma unroll
      for (int kk = 0; kk < 2; ++kk)
        pa[kk] = *(const short8*)&lPw[lr*64 + (((kk*4 + grp) ^ swz) * 8)];

      // O^T += V^T P
#pragma unroll
      for (int dn = 0; dn < 4; ++dn) {
        const int d = dn*16 + lr;
#pragma unroll
        for (int kk = 0; kk < 2; ++kk) {
          const int gp = (kk*4 + grp) ^ (d & 7);
          short8 vf = *(const short8*)&lV[i][d*64 + gp*8];
          accO[dn] = __builtin_amdgcn_mfma_f32_16x16x32_bf16(vf, pa[kk], accO[dn], 0, 0, 0);
        }
      }
      __syncthreads();
    }
  }

  // epilogue: reduce lrow across the q-row's 4 lanes, write O^T
  float lt = lrow + __shfl_xor(lrow, 16);
  lt += __shfl_xor(lt, 32);
  const float inv = 1.0f / lt;
  const int token = b*2048 + qw0 + lr;
#pragma unroll
  for (int dn = 0; dn < 4; ++dn)
#pragma unroll
    for (int p2 = 0; p2 < 2; ++p2) {
      const unsigned pk = cvt_pk_bf16(accO[dn][2*p2] * inv, accO[dn][2*p2+1] * inv);
      *(unsigned*)&O[token*1024 + h*64 + dn*16 + grp*4 + 2*p2] = pk;
    }
#undef STAGEKV
}

// ---------------- launcher ----------------
extern "C" void kernel_launch(void* const* d_in, const int* in_sizes, int n_in,
                              void* d_out, int out_size, void* d_ws, size_t ws_size,
                              hipStream_t stream) {
  const float* x  = (const float*)d_in[0];
  const float* Wq = (const float*)d_in[1];
  const float* bq = (const float*)d_in[2];
  const float* Wk = (const float*)d_in[3];
  const float* bk = (const float*)d_in[4];
  const float* Wv = (const float*)d_in[5];
  const float* bv = (const float*)d_in[6];
  const float* Wo = (const float*)d_in[7];
  const float* bo = (const float*)d_in[8];
  float* out = (float*)d_out;

  char* ws = (char*)d_ws;
  u16* xb  = (u16*)(ws + 0);          // [4096][1024] bf16
  u16* wqb = (u16*)(ws + 8388608);
  u16* wkb = (u16*)(ws + 10485760);
  u16* wvb = (u16*)(ws + 12582912);
  u16* wob = (u16*)(ws + 14680064);
  u16* Qb  = (u16*)(ws + 16777216);   // [32][2048][64]
  u16* Kb  = (u16*)(ws + 25165824);   // [32][2048][64]
  u16* Vb  = (u16*)(ws + 33554432);   // [32][64][2048]
  u16* Ab  = (u16*)(ws + 41943040);   // [4096][1024]

  k_cvt_all<<<dim3(8192), 256, 0, stream>>>(x, Wq, Wk, Wv, Wo, xb, wqb, wkb, wvb, wob);

  k_gemm_qkv<<<dim3(768), 256, 0, stream>>>(xb, wqb, wkb, wvb, bq, bk, bv, Qb, Kb, Vb);

  k_attn<<<dim3(1024), 256, 0, stream>>>(Qb, Kb, Vb, Ab);

  k_gemm_o<<<dim3(512), 256, 0, stream>>>(Ab, wob, bo, out);
}

// Round 19
// 101.361 us; speedup vs baseline: 1.1251x; 1.0522x over previous
//
#include <hip/hip_runtime.h>

typedef unsigned short u16;
typedef __attribute__((ext_vector_type(8))) short short8;
typedef __attribute__((ext_vector_type(4))) float floatx4;

__device__ __forceinline__ u16 f2bf(float x){
  union { float f; unsigned u; } v; v.f = x;
  unsigned r = v.u + 0x7fffu + ((v.u >> 16) & 1u);
  return (u16)(r >> 16);
}

__device__ __forceinline__ unsigned cvt_pk_bf16(float lo, float hi){
  unsigned r;
  asm("v_cvt_pk_bf16_f32 %0, %1, %2" : "=v"(r) : "v"(lo), "v"(hi));
  return r;
}

// raw v_exp_f32: args bounded (defer-max THR=8); underflow->0 wanted. No OCML fixup.
__device__ __forceinline__ float exp2_raw(float x){
  float r;
  asm("v_exp_f32 %0, %1" : "=v"(r) : "v"(x));
  return r;
}

__device__ __forceinline__ void gld16(const u16* g, u16* l){
  __builtin_amdgcn_global_load_lds(
      (const __attribute__((address_space(1))) void*)g,
      (__attribute__((address_space(3))) void*)l, 16, 0, 0);
}

#define WAIT_BAR_V4() asm volatile("s_waitcnt vmcnt(4) lgkmcnt(0)\ns_barrier" ::: "memory")
#define WAIT_BAR_V3() asm volatile("s_waitcnt vmcnt(3) lgkmcnt(0)\ns_barrier" ::: "memory")
#define WAIT_BAR_V0() asm volatile("s_waitcnt vmcnt(0) lgkmcnt(0)\ns_barrier" ::: "memory")

// ---------------- fused fp32 -> bf16 convert (x + 4 weights, one launch) -------
__global__ void k_cvt_all(const float* __restrict__ x,
                          const float* __restrict__ wq, const float* __restrict__ wk,
                          const float* __restrict__ wv, const float* __restrict__ wo,
                          u16* __restrict__ xb, u16* __restrict__ wqb, u16* __restrict__ wkb,
                          u16* __restrict__ wvb, u16* __restrict__ wob){
  const int i = blockIdx.x * 256 + threadIdx.x;   // float4 index, total 2097152
  const float* s; u16* d; int off;
  if (i < 1048576) { s = x; d = xb; off = i; }
  else {
    const int j = i - 1048576;
    const int wsel = j >> 18;          // 262144 f4 per weight
    off = j & 262143;
    s = (wsel==0) ? wq : (wsel==1) ? wk : (wsel==2) ? wv : wo;
    d = (wsel==0) ? wqb : (wsel==1) ? wkb : (wsel==2) ? wvb : wob;
  }
  const float4 f = ((const float4*)s)[off];
  unsigned lo = (unsigned)f2bf(f.x) | ((unsigned)f2bf(f.y) << 16);
  unsigned hi = (unsigned)f2bf(f.z) | ((unsigned)f2bf(f.w) << 16);
  ((uint2*)d)[off] = make_uint2(lo, hi);
}

// ---------------- QKV GEMM: 128x128 tile, XCD-chunked, triple-buffered ----------
// Main loop = round-16 best. Epilogue: Q/K transposed through LDS -> 16B stores;
// V packed uint2. LDS pool 48KB reused for the 128x136 transpose tile (34.8KB).
__global__ __launch_bounds__(256) void k_gemm_qkv(
    const u16* __restrict__ A,
    const u16* __restrict__ Wq, const u16* __restrict__ Wk, const u16* __restrict__ Wv,
    const float* __restrict__ bq, const float* __restrict__ bk, const float* __restrict__ bv,
    u16* __restrict__ Qo, u16* __restrict__ Ko, u16* __restrict__ Vo)
{
  const int bid = (int)blockIdx.x;
  const int xcd = bid & 7;
  const int i5  = bid >> 3;                    // 0..95
  const int xb_ = ((xcd >> 2) << 2) + (i5 & 3);        // 0..7
  const int rest = i5 >> 2;                    // 0..23
  const int yb_ = ((xcd & 3) << 3) + (rest & 7);       // 0..31
  const int mode = rest >> 3;                  // 0..2

  const u16* W      = (mode==1) ? Wk : (mode==2) ? Wv : Wq;
  const float* bias = (mode==1) ? bk : (mode==2) ? bv : bq;

  __shared__ u16 lmem[24576];                  // 49152 B pool: lA | lB | transpose tile
#define LAP(buf) (lmem + (buf)*4096)
#define LBP(buf) (lmem + 12288 + (buf)*4096)

  const int tid  = threadIdx.x;
  const int row0 = yb_ * 128;
  const int col0 = xb_ * 128;

  const int srow = tid >> 2;
  const int sgp  = tid & 3;
  const int sgl  = sgp ^ ((srow >> 1) & 3);
  const u16* ga0 = A + (row0 + srow)      * 1024 + sgl * 8;
  const u16* ga1 = A + (row0 + srow + 64) * 1024 + sgl * 8;
  const u16* gb0 = W + (col0 + srow)      * 1024 + sgl * 8;
  const u16* gb1 = W + (col0 + srow + 64) * 1024 + sgl * 8;

  const int l  = tid & 63, w = tid >> 6;
  const int wr = w >> 1,  wc = w & 1;
  const int lr = l & 15,  grp = l >> 4;
  const int sw = (lr >> 1) & 3;
  int aoff[4], boff[4];
#pragma unroll
  for (int m = 0; m < 4; ++m) aoff[m] = (wr*64 + m*16 + lr)*32 + ((grp ^ sw) * 8);
#pragma unroll
  for (int n = 0; n < 4; ++n) boff[n] = (wc*64 + n*16 + lr)*32 + ((grp ^ sw) * 8);

  floatx4 acc[4][4];
#pragma unroll
  for (int m = 0; m < 4; ++m)
#pragma unroll
    for (int n = 0; n < 4; ++n) acc[m][n] = (floatx4){0.f, 0.f, 0.f, 0.f};

#define STAGE(buf, kt_) do { \
    const int k0_ = (kt_) * 32; \
    gld16(ga0 + k0_, LAP(buf) + tid*8); \
    gld16(ga1 + k0_, LAP(buf) + 2048 + tid*8); \
    gld16(gb0 + k0_, LBP(buf) + tid*8); \
    gld16(gb1 + k0_, LBP(buf) + 2048 + tid*8); \
  } while (0)

  STAGE(0, 0);
  STAGE(1, 1);
  asm volatile("s_waitcnt vmcnt(4)\ns_barrier" ::: "memory");

  for (int kt0 = 0; kt0 < 32; kt0 += 3) {
#pragma unroll
    for (int i = 0; i < 3; ++i) {              // i == buffer index (compile-time)
      const int kt = kt0 + i;
      if (kt >= 32) break;
      const bool st2 = (kt + 2 < 32);
      if (st2) STAGE((i + 2) % 3, kt + 2);
      short8 af[4], bf[4];
#pragma unroll
      for (int m = 0; m < 4; ++m) af[m] = *(const short8*)(LAP(i) + aoff[m]);
#pragma unroll
      for (int n = 0; n < 4; ++n) bf[n] = *(const short8*)(LBP(i) + boff[n]);
#pragma unroll
      for (int m = 0; m < 4; ++m)
#pragma unroll
        for (int n = 0; n < 4; ++n)
          acc[m][n] = __builtin_amdgcn_mfma_f32_16x16x32_bf16(af[m], bf[n], acc[m][n], 0, 0, 0);
      if (st2) WAIT_BAR_V4(); else WAIT_BAR_V0();
    }
  }
#undef STAGE

  if (mode == 2) {
    // V -> [bh][64][s]: j-quad (consecutive s5) packed as one uint2 (8B) store
#pragma unroll
    for (int n = 0; n < 4; ++n) {
      const int cg = col0 + wc*64 + n*16 + lr;
      const float bb = bias[cg];
      const int h = cg >> 6, d = cg & 63;
#pragma unroll
      for (int m = 0; m < 4; ++m) {
        const int rg = row0 + wr*64 + m*16 + grp*4;
        const int b = rg >> 11, s5 = rg & 2047;
        uint2 val;
        val.x = cvt_pk_bf16(acc[m][n][0] + bb, acc[m][n][1] + bb);
        val.y = cvt_pk_bf16(acc[m][n][2] + bb, acc[m][n][3] + bb);
        *(uint2*)&Vo[(size_t)((b*16 + h)*64 + d)*2048 + s5] = val;
      }
    }
  } else {
    // Q/K -> [bh][s][64]: transpose through LDS, then 16B contiguous stores.
    const float sc = (mode == 0) ? 0.18033688011112042f : 1.0f;  // 0.125*log2(e)
    u16* dst = (mode == 0) ? Qo : Ko;
    u16* lT = lmem;                            // [128 rows][136 cols] u16 (34816 B)
    // final loop iter ended with WAIT_BAR_V0 -> all LDS traffic done; pool free
#pragma unroll
    for (int n = 0; n < 4; ++n) {
      const int cl = wc*64 + n*16 + lr;
      const float bb = bias[col0 + cl];
#pragma unroll
      for (int m = 0; m < 4; ++m) {
#pragma unroll
        for (int j = 0; j < 4; ++j) {
          const int row = wr*64 + m*16 + grp*4 + j;
          lT[row*136 + cl] = f2bf((acc[m][n][j] + bb) * sc);
        }
      }
    }
    __syncthreads();
    const int c8 = l & 15;                     // 16 col-chunks of 8
    const int rsub = w*4 + (l >> 4);           // 16 rows per pass
    const int hh = (col0 >> 6) + (c8 >> 3);
    const int dd = (c8 & 7) * 8;
#pragma unroll
    for (int p = 0; p < 8; ++p) {
      const int row = p*16 + rsub;
      const int rg = row0 + row;
      const int b = rg >> 11, s5 = rg & 2047;
      short8 v = *(const short8*)&lT[row*136 + c8*8];
      *(short8*)&dst[(size_t)((b*16 + hh)*2048 + s5)*64 + dd] = v;
    }
  }
#undef LAP
#undef LBP
}

// ---------------- O-proj GEMM: 64x128 tile, XCD-chunked, triple-buffered --------
__global__ __launch_bounds__(256) void k_gemm_o(
    const u16* __restrict__ A, const u16* __restrict__ W,
    const float* __restrict__ bias, float* __restrict__ Fo)
{
  const int bid = (int)blockIdx.x;
  const int xcd = bid & 7;
  const int i5  = bid >> 3;                    // 0..63
  const int xb_ = ((xcd >> 2) << 2) + (i5 & 3);        // 0..7
  const int yb_ = ((xcd & 3) << 4) + (i5 >> 2);        // 0..63

  __shared__ u16 lA[3][2048];
  __shared__ u16 lB[3][4096];

  const int tid  = threadIdx.x;
  const int row0 = yb_ * 64;
  const int col0 = xb_ * 128;

  const int srow = tid >> 2;
  const int sgp  = tid & 3;
  const int sgl  = sgp ^ ((srow >> 1) & 3);
  const u16* ga0 = A + (row0 + srow)      * 1024 + sgl * 8;
  const u16* gb0 = W + (col0 + srow)      * 1024 + sgl * 8;
  const u16* gb1 = W + (col0 + srow + 64) * 1024 + sgl * 8;

  const int l  = tid & 63, w = tid >> 6;
  const int wr = w >> 1,  wc = w & 1;
  const int lr = l & 15,  grp = l >> 4;
  const int sw = (lr >> 1) & 3;
  int aoff[2], boff[4];
#pragma unroll
  for (int m = 0; m < 2; ++m) aoff[m] = (wr*32 + m*16 + lr)*32 + ((grp ^ sw) * 8);
#pragma unroll
  for (int n = 0; n < 4; ++n) boff[n] = (wc*64 + n*16 + lr)*32 + ((grp ^ sw) * 8);

  floatx4 acc[2][4];
#pragma unroll
  for (int m = 0; m < 2; ++m)
#pragma unroll
    for (int n = 0; n < 4; ++n) acc[m][n] = (floatx4){0.f, 0.f, 0.f, 0.f};

#define STAGE(buf, kt_) do { \
    const int k0_ = (kt_) * 32; \
    gld16(ga0 + k0_, &lA[(buf)][tid*8]); \
    gld16(gb0 + k0_, &lB[(buf)][tid*8]); \
    gld16(gb1 + k0_, &lB[(buf)][2048 + tid*8]); \
  } while (0)

  STAGE(0, 0);
  STAGE(1, 1);
  asm volatile("s_waitcnt vmcnt(3)\ns_barrier" ::: "memory");

  for (int kt0 = 0; kt0 < 32; kt0 += 3) {
#pragma unroll
    for (int i = 0; i < 3; ++i) {
      const int kt = kt0 + i;
      if (kt >= 32) break;
      const bool st2 = (kt + 2 < 32);
      if (st2) STAGE((i + 2) % 3, kt + 2);
      short8 af[2], bf[4];
#pragma unroll
      for (int m = 0; m < 2; ++m) af[m] = *(const short8*)&lA[i][aoff[m]];
#pragma unroll
      for (int n = 0; n < 4; ++n) bf[n] = *(const short8*)&lB[i][boff[n]];
#pragma unroll
      for (int m = 0; m < 2; ++m)
#pragma unroll
        for (int n = 0; n < 4; ++n)
          acc[m][n] = __builtin_amdgcn_mfma_f32_16x16x32_bf16(af[m], bf[n], acc[m][n], 0, 0, 0);
      if (st2) WAIT_BAR_V3(); else WAIT_BAR_V0();
    }
  }
#undef STAGE

#pragma unroll
  for (int n = 0; n < 4; ++n) {
    const int cg = col0 + wc*64 + n*16 + lr;
    const float bb = bias[cg];
#pragma unroll
    for (int m = 0; m < 2; ++m) {
      const int rg = row0 + wr*32 + m*16 + grp*4;
#pragma unroll
      for (int j = 0; j < 4; ++j)
        Fo[(rg + j) * 1024 + cg] = acc[m][n][j] + bb;
    }
  }
}

// ---------------- flash attention (round-16 best: balanced blocks + THR=8) ------
__global__ __launch_bounds__(256, 4) void k_attn(
    const u16* __restrict__ Q, const u16* __restrict__ K,
    const u16* __restrict__ V, u16* __restrict__ O)
{
  __shared__ u16 lK[2][4096];     // [64 keys][64 dk] groups-of-8 swizzled
  __shared__ u16 lV[2][4096];     // [64 dk][64 keys] (V^T) swizzled
  __shared__ u16 lP[4][1024];     // [wave][16 q][64 keys] (wave-private)

  const int tid = threadIdx.x;
  const int bid = (int)blockIdx.x;
  const int xcd = bid & 7, r = bid >> 3;       // 128 blocks per XCD
  const int k_ = r & 31, j_ = r >> 5;          // CU index within XCD, slot 0..3
  const int bh = xcd * 4 + j_;                 // 4 bh per XCD -> K/V L2-resident
  const int qt = (j_ & 1) ? k_ : (31 - k_);    // per-CU phases: 66 for all CUs

  const int l = tid & 63, w = tid >> 6;
  const int lr = l & 15, grp = l >> 4;
  const int qw0 = qt * 64 + w * 16;
  const int nkt = qt + 1;

  const u16* Qh = Q + (size_t)bh * 2048 * 64;
  const u16* Kh = K + (size_t)bh * 2048 * 64;
  const u16* Vh = V + (size_t)bh * 64 * 2048;

  const int srow = tid >> 3, sgp = tid & 7;
  const int sgl = sgp ^ (srow & 7);
  u16* lPw = &lP[w][0];
  const int swz = lr & 7;
  const int b = bh >> 4, h = bh & 15;

#define STAGEKV(buf, kt_) do { \
    gld16(Kh + ((kt_)*64 + srow     )*64 + sgl*8, &lK[(buf)][tid*8]); \
    gld16(Kh + ((kt_)*64 + srow + 32)*64 + sgl*8, &lK[(buf)][2048 + tid*8]); \
    gld16(Vh + (srow     )*2048 + (kt_)*64 + sgl*8, &lV[(buf)][tid*8]); \
    gld16(Vh + (srow + 32)*2048 + (kt_)*64 + sgl*8, &lV[(buf)][2048 + tid*8]); \
  } while (0)

  short8 qf[2];
#pragma unroll
  for (int kk = 0; kk < 2; ++kk)
    qf[kk] = *(const short8*)(Qh + (qw0 + lr)*64 + kk*32 + grp*8);

  floatx4 accO[4];                 // O^T: [d=dn*16+grp*4+j][q=lr]
  float mrow = -1e30f, lrow = 0.f; // lrow = per-lane PARTIAL (this lane's keys)
#pragma unroll
  for (int dn = 0; dn < 4; ++dn) accO[dn] = (floatx4){0.f, 0.f, 0.f, 0.f};

  STAGEKV(0, 0);
  __syncthreads();

  for (int kt0 = 0; kt0 < nkt; kt0 += 2) {
#pragma unroll
    for (int i = 0; i < 2; ++i) {              // i == buffer index (compile-time)
      const int kt = kt0 + i;
      if (kt >= nkt) break;                    // nkt block-uniform -> barrier-safe
      if (kt + 1 < nkt) STAGEKV(i ^ 1, kt + 1);
      const int kb = kt * 64;

      // S^T = K Q^T : st[n] reg j -> key = kb+n*16+grp*4+j, query = qw0+lr
      floatx4 st[4];
#pragma unroll
      for (int n = 0; n < 4; ++n) st[n] = (floatx4){0.f, 0.f, 0.f, 0.f};
#pragma unroll
      for (int n = 0; n < 4; ++n) {
        const int key = n*16 + lr;
#pragma unroll
        for (int kk = 0; kk < 2; ++kk) {
          const int gp = (kk*4 + grp) ^ (key & 7);
          short8 kf = *(const short8*)&lK[i][key*64 + gp*8];
          st[n] = __builtin_amdgcn_mfma_f32_16x16x32_bf16(kf, qf[kk], st[n], 0, 0, 0);
        }
      }

      // causal mask (only diagonal tile kt==qt is partial)
      const int lim = qw0 + lr - kb;
      if (63 > lim) {
#pragma unroll
        for (int n = 0; n < 4; ++n)
#pragma unroll
          for (int jj = 0; jj < 4; ++jj)
            if (n*16 + grp*4 + jj > lim) st[n][jj] = -1e30f;
      }

      // defer-max online softmax (T13, THR=8): allow P up to 2^8 before rescaling.
      float mt = st[0][0];
#pragma unroll
      for (int n = 0; n < 4; ++n)
#pragma unroll
        for (int jj = 0; jj < 4; ++jj) mt = fmaxf(mt, st[n][jj]);
      if (!__all(mt <= mrow + 8.0f)) {
        float mg = fmaxf(mt, __shfl_xor(mt, 16));
        mg = fmaxf(mg, __shfl_xor(mg, 32));
        const float mn = fmaxf(mrow, mg);
        const float alpha = exp2_raw(mrow - mn);
        mrow = mn;
        lrow *= alpha;
#pragma unroll
        for (int dn = 0; dn < 4; ++dn) accO[dn] *= alpha;
      }
      float ps = 0.f;
#pragma unroll
      for (int n = 0; n < 4; ++n)
#pragma unroll
        for (int jj = 0; jj < 4; ++jj) {
          const float p = exp2_raw(st[n][jj] - mrow);
          st[n][jj] = p;
          ps += p;
        }
      lrow += ps;                  // per-lane partial; reduced once in epilogue

      // pack P -> wave-private LDS [q][key], swizzled groups-of-8
#pragma unroll
      for (int n = 0; n < 4; ++n)
#pragma unroll
        for (int p2 = 0; p2 < 2; ++p2) {
          const unsigned pk = cvt_pk_bf16(st[n][2*p2], st[n][2*p2+1]);
          const int pg = (2*n + (grp >> 1)) ^ swz;
          ((unsigned*)lPw)[lr*32 + pg*4 + (grp & 1)*2 + p2] = pk;
        }

      asm volatile("s_waitcnt lgkmcnt(0)" ::: "memory");

      short8 pa[2];
#pragma unroll
      for (int kk = 0; kk < 2; ++kk)
        pa[kk] = *(const short8*)&lPw[lr*64 + (((kk*4 + grp) ^ swz) * 8)];

      // O^T += V^T P
#pragma unroll
      for (int dn = 0; dn < 4; ++dn) {
        const int d = dn*16 + lr;
#pragma unroll
        for (int kk = 0; kk < 2; ++kk) {
          const int gp = (kk*4 + grp) ^ (d & 7);
          short8 vf = *(const short8*)&lV[i][d*64 + gp*8];
          accO[dn] = __builtin_amdgcn_mfma_f32_16x16x32_bf16(vf, pa[kk], accO[dn], 0, 0, 0);
        }
      }
      __syncthreads();
    }
  }

  // epilogue: reduce lrow across the q-row's 4 lanes, write O^T
  float lt = lrow + __shfl_xor(lrow, 16);
  lt += __shfl_xor(lt, 32);
  const float inv = 1.0f / lt;
  const int token = b*2048 + qw0 + lr;
#pragma unroll
  for (int dn = 0; dn < 4; ++dn)
#pragma unroll
    for (int p2 = 0; p2 < 2; ++p2) {
      const unsigned pk = cvt_pk_bf16(accO[dn][2*p2] * inv, accO[dn][2*p2+1] * inv);
      *(unsigned*)&O[token*1024 + h*64 + dn*16 + grp*4 + 2*p2] = pk;
    }
#undef STAGEKV
}

// ---------------- launcher ----------------
extern "C" void kernel_launch(void* const* d_in, const int* in_sizes, int n_in,
                              void* d_out, int out_size, void* d_ws, size_t ws_size,
                              hipStream_t stream) {
  const float* x  = (const float*)d_in[0];
  const float* Wq = (const float*)d_in[1];
  const float* bq = (const float*)d_in[2];
  const float* Wk = (const float*)d_in[3];
  const float* bk = (const float*)d_in[4];
  const float* Wv = (const float*)d_in[5];
  const float* bv = (const float*)d_in[6];
  const float* Wo = (const float*)d_in[7];
  const float* bo = (const float*)d_in[8];
  float* out = (float*)d_out;

  char* ws = (char*)d_ws;
  u16* xb  = (u16*)(ws + 0);          // [4096][1024] bf16
  u16* wqb = (u16*)(ws + 8388608);
  u16* wkb = (u16*)(ws + 10485760);
  u16* wvb = (u16*)(ws + 12582912);
  u16* wob = (u16*)(ws + 14680064);
  u16* Qb  = (u16*)(ws + 16777216);   // [32][2048][64]
  u16* Kb  = (u16*)(ws + 25165824);   // [32][2048][64]
  u16* Vb  = (u16*)(ws + 33554432);   // [32][64][2048]
  u16* Ab  = (u16*)(ws + 41943040);   // [4096][1024]

  k_cvt_all<<<dim3(8192), 256, 0, stream>>>(x, Wq, Wk, Wv, Wo, xb, wqb, wkb, wvb, wob);

  k_gemm_qkv<<<dim3(768), 256, 0, stream>>>(xb, wqb, wkb, wvb, bq, bk, bv, Qb, Kb, Vb);

  k_attn<<<dim3(1024), 256, 0, stream>>>(Qb, Kb, Vb, Ab);

  k_gemm_o<<<dim3(512), 256, 0, stream>>>(Ab, wob, bo, out);
}